// Round 4
// baseline (305.659 us; speedup 1.0000x reference)
//
#include <hip/hip_runtime.h>
#include <hip/hip_bf16.h>

typedef unsigned short u16;
typedef __attribute__((ext_vector_type(8))) short bf16x8;
typedef __attribute__((ext_vector_type(4))) float f32x4;

__device__ __forceinline__ float bf2f(u16 u){
  union { unsigned int i; float f; } v; v.i = ((unsigned int)u) << 16; return v.f;
}
__device__ __forceinline__ u16 f2bf(float f){
  union { float f; unsigned int i; } v; v.f = f;
  unsigned int i = v.i;
  return (u16)((i + 0x7fffu + ((i >> 16) & 1u)) >> 16);
}
// packed bf16 convert (v_cvt_pk_bf16_f32 on gfx950)
__device__ __forceinline__ unsigned int pk2(float a, float b){
  union { __hip_bfloat162 v; unsigned int u; } c;
  c.v = __float22bfloat162_rn(float2{a, b});
  return c.u;
}
__device__ __forceinline__ float ldin(const void* p, int i, int f){
  return f ? ((const float*)p)[i] : bf2f(((const u16*)p)[i]);
}

// ---------------------------------------------------------------------------
// Kernel S: sniff input dtype from msa_act's first 256 words.
// ---------------------------------------------------------------------------
__global__ void k_sniff(const unsigned int* __restrict__ msa_w, int* __restrict__ flag)
{
  int lane = threadIdx.x & 63;
  int lo0 = 0, expok = 0;
  #pragma unroll
  for (int j = 0; j < 4; ++j) {
    unsigned int w = msa_w[lane * 4 + j];
    if ((w & 0xffffu) == 0u) lo0++;
    unsigned int e = (w >> 7) & 0xffu;
    if (e >= 110u && e <= 140u) expok++;
  }
  #pragma unroll
  for (int off = 1; off < 64; off <<= 1) {
    lo0   += __shfl_xor(lo0,   off, 64);
    expok += __shfl_xor(expok, off, 64);
  }
  if (lane == 0 && blockIdx.x == 0)
    *flag = (lo0 > 200) ? 1 : ((expok > 200) ? 0 : 1);
}

// ---------------------------------------------------------------------------
// Kernel 0: LDS-tiled coalesced transpose of the 5 weight matrices -> bf16.
// ---------------------------------------------------------------------------
__global__ __launch_bounds__(256) void k_transpose(
    const void* __restrict__ wq, const void* __restrict__ wk,
    const void* __restrict__ wv, const void* __restrict__ wg,
    const void* __restrict__ wo, const int* __restrict__ flagp,
    u16* __restrict__ Wt, u16* __restrict__ wot)
{
  __shared__ u16 T[64 * 72];
  const int flag = *flagp;
  const int t = threadIdx.x;
  const int mat = blockIdx.x >> 4, tile = blockIdx.x & 15;
  const int R0 = (tile >> 2) * 64, C0 = (tile & 3) * 64;
  const void* src = (mat == 0) ? wq : (mat == 1) ? wk : (mat == 2) ? wv
                  : (mat == 3) ? wg : wo;
  u16* dst = (mat < 4) ? (Wt + mat * 65536) : wot;
  {
    int i = t >> 2, j0 = (t & 3) * 16;
    #pragma unroll
    for (int e = 0; e < 8; ++e) {
      float a = ldin(src, (R0 + i) * 256 + C0 + j0 + 2*e,     flag);
      float b = ldin(src, (R0 + i) * 256 + C0 + j0 + 2*e + 1, flag);
      *(unsigned int*)(T + i * 72 + j0 + 2*e) = pk2(a, b);
    }
  }
  __syncthreads();
  {
    int j = t >> 2, i0 = (t & 3) * 16;
    u16 o[16];
    #pragma unroll
    for (int e = 0; e < 16; ++e) o[e] = T[(i0 + e) * 72 + j];
    *(uint4*)(dst + (C0 + j) * 256 + R0 + i0)     = *(const uint4*)o;
    *(uint4*)(dst + (C0 + j) * 256 + R0 + i0 + 8) = *(const uint4*)(o + 8);
  }
}

// ---------------------------------------------------------------------------
// Kernel 1: pair LayerNorm + z[h][q*256+k] via MFMA -> bf16 (1 MB total).
// ---------------------------------------------------------------------------
__global__ __launch_bounds__(256) void k_pair_z(
    const void* __restrict__ pair, const void* __restrict__ png,
    const void* __restrict__ pnb, const void* __restrict__ w2d,
    const int* __restrict__ flagp, u16* __restrict__ z_bf)
{
  __shared__ u16 As[64 * 136];
  __shared__ u16 Bs[16 * 136];
  const int flag = *flagp;
  const int t = threadIdx.x, lane = t & 63, wave = t >> 6;
  const int g = lane >> 4, l15 = lane & 15;
  const int rowBase = blockIdx.x * 64;          // of 65536 (q*256+k)

  if (t < 128) {
    #pragma unroll
    for (int n = 0; n < 16; ++n)
      Bs[n * 136 + t] = (n < 8) ? f2bf(ldin(w2d, t * 8 + n, flag)) : (u16)0;
  }
  {
    int lrow = t >> 2, cb = (t & 3) * 32;
    int base = (rowBase + lrow) * 128 + cb;
    float x[32];
    if (flag) {
      const float* p = (const float*)pair + base;
      #pragma unroll
      for (int j = 0; j < 8; ++j) {
        float4 f4 = *(const float4*)(p + 4 * j);
        x[4*j] = f4.x; x[4*j+1] = f4.y; x[4*j+2] = f4.z; x[4*j+3] = f4.w;
      }
    } else {
      const u16* p = (const u16*)pair + base;
      #pragma unroll
      for (int j = 0; j < 4; ++j) {
        uint4 u = *(const uint4*)(p + 8 * j);
        const u16* h = (const u16*)&u;
        #pragma unroll
        for (int e = 0; e < 8; ++e) x[8*j+e] = bf2f(h[e]);
      }
    }
    float s = 0.f, sq = 0.f;
    #pragma unroll
    for (int j = 0; j < 32; ++j) { s += x[j]; sq += x[j] * x[j]; }
    s  += __shfl_xor(s, 1, 64);  s  += __shfl_xor(s, 2, 64);
    sq += __shfl_xor(sq, 1, 64); sq += __shfl_xor(sq, 2, 64);
    float mu = s * (1.f / 128.f);
    float var = sq * (1.f / 128.f) - mu * mu;
    float rs = rsqrtf(var + 1e-5f);
    float n_[32];
    #pragma unroll
    for (int j = 0; j < 32; ++j) {
      int c = cb + j;
      n_[j] = (x[j] - mu) * rs * ldin(png, c, flag) + ldin(pnb, c, flag);
    }
    u16* dst = As + lrow * 136 + cb;
    #pragma unroll
    for (int j = 0; j < 16; ++j)
      *(unsigned int*)(dst + 2*j) = pk2(n_[2*j], n_[2*j+1]);
  }
  __syncthreads();

  f32x4 accz = {0.f, 0.f, 0.f, 0.f};
  #pragma unroll
  for (int kb = 0; kb < 4; ++kb) {
    bf16x8 a = *(const bf16x8*)(As + (wave * 16 + l15) * 136 + kb * 32 + g * 8);
    bf16x8 b = *(const bf16x8*)(Bs + l15 * 136 + kb * 32 + g * 8);
    accz = __builtin_amdgcn_mfma_f32_16x16x32_bf16(a, b, accz, 0, 0, 0);
  }
  if (l15 < 8) {
    #pragma unroll
    for (int r = 0; r < 4; ++r)
      z_bf[l15 * 65536 + rowBase + wave * 16 + g * 4 + r] = f2bf(accz[r]);
  }
}

// ---------------------------------------------------------------------------
// Kernel 2: msa LayerNorm fully applied -> m_bf16.
// ---------------------------------------------------------------------------
__global__ __launch_bounds__(256) void k_msa_ln(
    const void* __restrict__ msa, const void* __restrict__ qng,
    const void* __restrict__ qnb, const int* __restrict__ flagp,
    u16* __restrict__ m_bf)
{
  const int flag = *flagp;
  int wave = threadIdx.x >> 6, lane = threadIdx.x & 63;
  int row = blockIdx.x * 4 + wave;              // 0..32767
  float x[4];
  if (flag) {
    float4 f4 = *((const float4*)msa + row * 64 + lane);
    x[0]=f4.x; x[1]=f4.y; x[2]=f4.z; x[3]=f4.w;
  } else {
    uint2 u = *((const uint2*)msa + row * 64 + lane);
    const u16* h = (const u16*)&u;
    #pragma unroll
    for (int j = 0; j < 4; ++j) x[j] = bf2f(h[j]);
  }
  float s = 0.f, sq = 0.f;
  #pragma unroll
  for (int j = 0; j < 4; ++j) { s += x[j]; sq += x[j] * x[j]; }
  #pragma unroll
  for (int off = 1; off < 64; off <<= 1) {
    s  += __shfl_xor(s,  off, 64);
    sq += __shfl_xor(sq, off, 64);
  }
  float mu = s * (1.f / 256.f);
  float var = sq * (1.f / 256.f) - mu * mu;
  float rs = rsqrtf(var + 1e-5f);
  float y[4];
  #pragma unroll
  for (int j = 0; j < 4; ++j) {
    int c = lane * 4 + j;
    y[j] = (x[j] - mu) * rs * ldin(qng, c, flag) + ldin(qnb, c, flag);
  }
  uint2 o2;
  o2.x = pk2(y[0], y[1]);
  o2.y = pk2(y[2], y[3]);
  *((uint2*)m_bf + row * 64 + lane) = o2;
}

// ---------------------------------------------------------------------------
// Kernel 3: FUSED projections + attention, one block per (s,h).
// Round-12 (re-phase): R0's dense-issue phasing restored on top of the
// R3 spill-free structure.  Per qt: (1) 16 INDEPENDENT QK MFMAs -> S[16]
// (AGPRs, latencies mutually hidden), (2) one softmax pass (64 exp, pack
// to pw[8][4], no MFMA interleaved), (3) dense PV with even/odd-kc split
// accumulators (4 chains -> half the dependent-MFMA chain length).
// Projections stay R3-streamed (spill-free); swapped-QK pi layout
// unchanged (verified R1-R3).  LDS 38.4 KB.
// ---------------------------------------------------------------------------
__global__ __launch_bounds__(256, 2) void k_fused(
    const u16* __restrict__ m_bf, const u16* __restrict__ Wt,
    const void* __restrict__ bg, const u16* __restrict__ z_bf,
    const void* __restrict__ mask, const int* __restrict__ flagp,
    u16* __restrict__ og_ws)
{
  __shared__ u16 Ks[256 * 40];        // [k][d] pad 40        (20480 B)
  __shared__ u16 Vts[32 * 264];       // [d][k] pad 264       (16896 B)
  __shared__ float Mb[256];           // mask bias            ( 1024 B)
  const int flag = *flagp;
  const int t = threadIdx.x, lane = t & 63, wave = t >> 6;
  const int s_ = blockIdx.x, h = blockIdx.y;
  const int g = lane >> 4, l15 = lane & 15;

  Mb[t] = 1e9f * (ldin(mask, s_ * 256 + t, flag) - 1.0f);

  const float scale = 0.17677669529663687f;  // 1/sqrt(32)
  f32x4 zero = {0.f, 0.f, 0.f, 0.f};
  const u16* mrow = m_bf + (s_ * 256 + wave * 64) * 256;

  unsigned int qp[4][4];
  float gg[4][2][4];

  // 4 projections: matid 0=q(swapped) 1=k 2=v(swapped) 3=g.
  // Runtime loop: one matid's working set live at a time (~60 VGPR).
  #pragma clang loop unroll(disable)
  for (int matid = 0; matid < 4; ++matid) {
    const u16* W = Wt + matid * 65536 + (h * 32) * 256;  // [d][c] rows
    f32x4 acc[4][2];
    #pragma unroll
    for (int mt = 0; mt < 4; ++mt) { acc[mt][0] = zero; acc[mt][1] = zero; }
    if (matid == 0 || matid == 2) {
      #pragma unroll
      for (int kb = 0; kb < 8; ++kb) {
        bf16x8 a[4];
        #pragma unroll
        for (int mt = 0; mt < 4; ++mt)
          a[mt] = *(const bf16x8*)(mrow + (mt * 16 + l15) * 256 + kb * 32 + g * 8);
        bf16x8 b0 = *(const bf16x8*)(W + l15 * 256        + kb * 32 + g * 8);
        bf16x8 b1 = *(const bf16x8*)(W + (16 + l15) * 256 + kb * 32 + g * 8);
        // swapped: D[d][m-row]: out row g*4+r = d, out col l15 = m-row
        #pragma unroll
        for (int mt = 0; mt < 4; ++mt) {
          acc[mt][0] = __builtin_amdgcn_mfma_f32_16x16x32_bf16(b0, a[mt], acc[mt][0], 0, 0, 0);
          acc[mt][1] = __builtin_amdgcn_mfma_f32_16x16x32_bf16(b1, a[mt], acc[mt][1], 0, 0, 0);
        }
      }
    } else {
      #pragma unroll
      for (int kb = 0; kb < 8; ++kb) {
        bf16x8 a[4];
        #pragma unroll
        for (int mt = 0; mt < 4; ++mt)
          a[mt] = *(const bf16x8*)(mrow + (mt * 16 + l15) * 256 + kb * 32 + g * 8);
        bf16x8 b0 = *(const bf16x8*)(W + l15 * 256        + kb * 32 + g * 8);
        bf16x8 b1 = *(const bf16x8*)(W + (16 + l15) * 256 + kb * 32 + g * 8);
        // normal: out row g*4+r = m-row, out col l15 = d
        #pragma unroll
        for (int mt = 0; mt < 4; ++mt) {
          acc[mt][0] = __builtin_amdgcn_mfma_f32_16x16x32_bf16(a[mt], b0, acc[mt][0], 0, 0, 0);
          acc[mt][1] = __builtin_amdgcn_mfma_f32_16x16x32_bf16(a[mt], b1, acc[mt][1], 0, 0, 0);
        }
      }
    }
    if (matid == 0) {
      // Q in pi layout: lane holds q = mt*16+l15, d-slots g*4+r / 16+g*4+r
      #pragma unroll
      for (int mt = 0; mt < 4; ++mt) {
        qp[mt][0] = pk2(acc[mt][0][0] * scale, acc[mt][0][1] * scale);
        qp[mt][1] = pk2(acc[mt][0][2] * scale, acc[mt][0][3] * scale);
        qp[mt][2] = pk2(acc[mt][1][0] * scale, acc[mt][1][1] * scale);
        qp[mt][3] = pk2(acc[mt][1][2] * scale, acc[mt][1][3] * scale);
      }
    } else if (matid == 1) {
      #pragma unroll
      for (int mt = 0; mt < 4; ++mt)
        #pragma unroll
        for (int r = 0; r < 4; ++r) {
          int rowl = wave * 64 + mt * 16 + g * 4 + r;   // k row 0..255
          Ks[rowl * 40 + l15]      = f2bf(acc[mt][0][r]);
          Ks[rowl * 40 + 16 + l15] = f2bf(acc[mt][1][r]);
        }
    } else if (matid == 2) {
      // swapped V: lane holds k = wave*64+mt*16+l15, d = g*4+r / 16+g*4+r
      #pragma unroll
      for (int mt = 0; mt < 4; ++mt)
        #pragma unroll
        for (int r = 0; r < 4; ++r) {
          int kcol = wave * 64 + mt * 16 + l15;
          Vts[(g * 4 + r) * 264 + kcol]      = f2bf(acc[mt][0][r]);
          Vts[(16 + g * 4 + r) * 264 + kcol] = f2bf(acc[mt][1][r]);
        }
    } else {
      #pragma unroll
      for (int mt = 0; mt < 4; ++mt)
        #pragma unroll
        for (int nt = 0; nt < 2; ++nt)
          #pragma unroll
          for (int r = 0; r < 4; ++r) {
            float gv = acc[mt][nt][r] + ldin(bg, h * 32 + nt * 16 + l15, flag);
            gg[mt][nt][r] = 1.0f / (1.0f + __expf(-gv));
          }
    }
  }
  __syncthreads();

  // ---- attention: phased, in-register softmax (q = l15 per lane) ----
  #pragma unroll
  for (int qt = 0; qt < 4; ++qt) {
    __builtin_amdgcn_sched_barrier(0);   // no cross-qt hoisting (reg pressure)
    const int qbase = wave * 64 + qt * 16;      // q within s (0..255)
    const u16* zb = z_bf + h * 65536 + (qbase + l15) * 256;
    uint2 zu[16];
    #pragma unroll
    for (int kt = 0; kt < 16; ++kt)
      zu[kt] = *(const uint2*)(zb + kt * 16 + g * 4);

    union { bf16x8 v; unsigned int w[4]; } aq;
    aq.w[0] = qp[qt][0]; aq.w[1] = qp[qt][1];
    aq.w[2] = qp[qt][2]; aq.w[3] = qp[qt][3];

    // Phase 1: dense QK — 16 independent MFMAs (latencies mutually hidden)
    f32x4 S[16];
    #pragma unroll
    for (int kt = 0; kt < 16; ++kt) {
      union { bf16x8 v; uint2 u2[2]; } kf;
      const u16* kr = Ks + (kt * 16 + l15) * 40;
      kf.u2[0] = *(const uint2*)(kr + g * 4);
      kf.u2[1] = *(const uint2*)(kr + 16 + g * 4);
      // St: col l15 = q, row g*4+r = k within kt
      S[kt] = __builtin_amdgcn_mfma_f32_16x16x32_bf16(kf.v, aq.v, zero, 0, 0, 0);
    }

    // Phase 2: softmax (no max-pass: logits bounded; masked -> exp(-1e9)=0)
    float sm = 0.f;
    unsigned int pw[8][4];
    #pragma unroll
    for (int kc = 0; kc < 8; ++kc) {
      #pragma unroll
      for (int half = 0; half < 2; ++half) {
        const int kt = kc * 2 + half;
        float4 mb = *(const float4*)(Mb + kt * 16 + g * 4);
        const u16* zh = (const u16*)&zu[kt];
        float e0 = __expf(S[kt][0] + mb.x + bf2f(zh[0]));
        float e1 = __expf(S[kt][1] + mb.y + bf2f(zh[1]));
        float e2 = __expf(S[kt][2] + mb.z + bf2f(zh[2]));
        float e3 = __expf(S[kt][3] + mb.w + bf2f(zh[3]));
        sm += (e0 + e1) + (e2 + e3);
        pw[kc][half * 2]     = pk2(e0, e1);
        pw[kc][half * 2 + 1] = pk2(e2, e3);
      }
    }

    // Phase 3: dense PV — even/odd kc accumulator split (4 chains)
    f32x4 O0a = zero, O0b = zero, O1a = zero, O1b = zero;
    #pragma unroll
    for (int kc = 0; kc < 8; ++kc) {
      union { bf16x8 v; unsigned int w[4]; } pf;
      pf.w[0] = pw[kc][0]; pf.w[1] = pw[kc][1];
      pf.w[2] = pw[kc][2]; pf.w[3] = pw[kc][3];
      union { bf16x8 v; uint2 u2[2]; } vf0, vf1;
      const u16* vr0 = Vts + l15 * 264 + kc * 32;
      const u16* vr1 = Vts + (16 + l15) * 264 + kc * 32;
      vf0.u2[0] = *(const uint2*)(vr0 + g * 4);
      vf0.u2[1] = *(const uint2*)(vr0 + 16 + g * 4);
      vf1.u2[0] = *(const uint2*)(vr1 + g * 4);
      vf1.u2[1] = *(const uint2*)(vr1 + 16 + g * 4);
      if (kc & 1) {
        O0b = __builtin_amdgcn_mfma_f32_16x16x32_bf16(pf.v, vf0.v, O0b, 0, 0, 0);
        O1b = __builtin_amdgcn_mfma_f32_16x16x32_bf16(pf.v, vf1.v, O1b, 0, 0, 0);
      } else {
        O0a = __builtin_amdgcn_mfma_f32_16x16x32_bf16(pf.v, vf0.v, O0a, 0, 0, 0);
        O1a = __builtin_amdgcn_mfma_f32_16x16x32_bf16(pf.v, vf1.v, O1a, 0, 0, 0);
      }
    }
    sm += __shfl_xor(sm, 16, 64);
    sm += __shfl_xor(sm, 32, 64);
    #pragma unroll
    for (int r = 0; r < 4; ++r) {
      float smr = __shfl(sm, g * 4 + r, 64);
      float inv = 1.0f / smr;
      int qq = qbase + g * 4 + r;
      int base = (s_ * 256 + qq) * 256 + h * 32;
      og_ws[base + l15]      = f2bf((O0a[r] + O0b[r]) * inv * gg[qt][0][r]);
      og_ws[base + 16 + l15] = f2bf((O1a[r] + O1b[r]) * inv * gg[qt][1][r]);
    }
  }
}

// ---------------------------------------------------------------------------
// Kernel 5: output projection GEMM.  Round-12: 64-row tiles, grid (512,2)
// = 1024 blocks, ~95 unified regs at launch_bounds(256,4) -> 4 blocks/CU
// for latency hiding.  M=32768, N=256, K=256. +bo.
// ---------------------------------------------------------------------------
__global__ __launch_bounds__(256, 4) void k_outproj(
    const u16* __restrict__ og, const u16* __restrict__ wot,
    const void* __restrict__ bo, const int* __restrict__ flagp,
    void* __restrict__ outv)
{
  const int flag = *flagp;
  const int t = threadIdx.x, lane = t & 63, wave = t >> 6;
  const int wm = (wave >> 1) * 32, wn = (wave & 1) * 64;
  const int rowBase = blockIdx.x * 64;
  const int ct = blockIdx.y;
  const int g = lane >> 4, l15 = lane & 15;

  bf16x8 af[8][2];
  #pragma unroll
  for (int kb = 0; kb < 8; ++kb)
    #pragma unroll
    for (int mt = 0; mt < 2; ++mt)
      af[kb][mt] = *(const bf16x8*)(
          og + (rowBase + wm + mt * 16 + l15) * 256 + kb * 32 + g * 8);

  const u16* Wb = wot + (ct * 128 + wn) * 256;
  f32x4 acc[2][4];
  f32x4 zero = {0.f, 0.f, 0.f, 0.f};
  #pragma unroll
  for (int i = 0; i < 2; ++i)
    #pragma unroll
    for (int j = 0; j < 4; ++j) acc[i][j] = zero;
  #pragma unroll
  for (int kb = 0; kb < 8; ++kb) {
    bf16x8 bb[4];
    #pragma unroll
    for (int nt = 0; nt < 4; ++nt)
      bb[nt] = *(const bf16x8*)(Wb + (nt * 16 + l15) * 256 + kb * 32 + g * 8);
    #pragma unroll
    for (int mt = 0; mt < 2; ++mt)
      #pragma unroll
      for (int nt = 0; nt < 4; ++nt)
        acc[mt][nt] = __builtin_amdgcn_mfma_f32_16x16x32_bf16(
            af[kb][mt], bb[nt], acc[mt][nt], 0, 0, 0);
  }
  #pragma unroll
  for (int mt = 0; mt < 2; ++mt)
    #pragma unroll
    for (int nt = 0; nt < 4; ++nt)
      #pragma unroll
      for (int r = 0; r < 4; ++r) {
        int row = rowBase + wm + mt * 16 + g * 4 + r;
        int col = ct * 128 + wn + nt * 16 + l15;
        float val = acc[mt][nt][r] + ldin(bo, col, flag);
        if (flag) ((float*)outv)[row * 256 + col] = val;
        else      ((u16*)outv)[row * 256 + col]   = f2bf(val);
      }
}

// ---------------------------------------------------------------------------
extern "C" void kernel_launch(void* const* d_in, const int* in_sizes, int n_in,
                              void* d_out, int out_size, void* d_ws, size_t ws_size,
                              hipStream_t stream)
{
  const void* msa  = d_in[0];
  const void* pair = d_in[1];
  const void* mask = d_in[2];
  const void* qng  = d_in[3];
  const void* qnb  = d_in[4];
  const void* png  = d_in[5];
  const void* pnb  = d_in[6];
  const void* w2d  = d_in[7];
  const void* wq   = d_in[8];
  const void* wk   = d_in[9];
  const void* wv   = d_in[10];
  const void* wg   = d_in[11];
  const void* bg   = d_in[12];
  const void* wo   = d_in[13];
  const void* bo   = d_in[14];

  char* ws = (char*)d_ws;
  u16* z_bf  = (u16*)(ws + 0);                  //  1,048,576
  u16* Wt    = (u16*)(ws + 1048576);            //    524,288
  u16* wot   = (u16*)(ws + 1572864);            //    131,072
  int* flag  = (int*)(ws + 1703936);            //        256
  u16* m_bf  = (u16*)(ws + 1704192);            // 16,777,216
  u16* og_ws = (u16*)(ws + 18481408);           // 16,777,216 -> ends 35,258,624

  hipLaunchKernelGGL(k_sniff, dim3(1), dim3(64), 0, stream,
                     (const unsigned int*)msa, flag);
  hipLaunchKernelGGL(k_transpose, dim3(80), dim3(256), 0, stream,
                     wq, wk, wv, wg, wo, flag, Wt, wot);
  hipLaunchKernelGGL(k_msa_ln, dim3(8192), dim3(256), 0, stream,
                     msa, qng, qnb, flag, m_bf);
  hipLaunchKernelGGL(k_pair_z, dim3(1024), dim3(256), 0, stream,
                     pair, png, pnb, w2d, flag, z_bf);
  hipLaunchKernelGGL(k_fused, dim3(128, 8), dim3(256), 0, stream,
                     m_bf, Wt, bg, z_bf, mask, flag, og_ws);
  hipLaunchKernelGGL(k_outproj, dim3(512, 2), dim3(256), 0, stream,
                     og_ws, wot, bo, flag, d_out);
}

// Round 5
// 266.427 us; speedup vs baseline: 1.1473x; 1.1473x over previous
//
#include <hip/hip_runtime.h>
#include <hip/hip_bf16.h>

typedef unsigned short u16;
typedef __attribute__((ext_vector_type(8))) short bf16x8;
typedef __attribute__((ext_vector_type(4))) float f32x4;

__device__ __forceinline__ float bf2f(u16 u){
  union { unsigned int i; float f; } v; v.i = ((unsigned int)u) << 16; return v.f;
}
__device__ __forceinline__ u16 f2bf(float f){
  union { float f; unsigned int i; } v; v.f = f;
  unsigned int i = v.i;
  return (u16)((i + 0x7fffu + ((i >> 16) & 1u)) >> 16);
}
// packed bf16 convert (v_cvt_pk_bf16_f32 on gfx950)
__device__ __forceinline__ unsigned int pk2(float a, float b){
  union { __hip_bfloat162 v; unsigned int u; } c;
  c.v = __float22bfloat162_rn(float2{a, b});
  return c.u;
}
__device__ __forceinline__ float ldin(const void* p, int i, int f){
  return f ? ((const float*)p)[i] : bf2f(((const u16*)p)[i]);
}

// ---------------------------------------------------------------------------
// Kernel S: sniff input dtype from msa_act's first 256 words.
// ---------------------------------------------------------------------------
__global__ void k_sniff(const unsigned int* __restrict__ msa_w, int* __restrict__ flag)
{
  int lane = threadIdx.x & 63;
  int lo0 = 0, expok = 0;
  #pragma unroll
  for (int j = 0; j < 4; ++j) {
    unsigned int w = msa_w[lane * 4 + j];
    if ((w & 0xffffu) == 0u) lo0++;
    unsigned int e = (w >> 7) & 0xffu;
    if (e >= 110u && e <= 140u) expok++;
  }
  #pragma unroll
  for (int off = 1; off < 64; off <<= 1) {
    lo0   += __shfl_xor(lo0,   off, 64);
    expok += __shfl_xor(expok, off, 64);
  }
  if (lane == 0 && blockIdx.x == 0)
    *flag = (lo0 > 200) ? 1 : ((expok > 200) ? 0 : 1);
}

// ---------------------------------------------------------------------------
// Kernel 0: LDS-tiled coalesced transpose of the 5 weight matrices -> bf16.
// ---------------------------------------------------------------------------
__global__ __launch_bounds__(256) void k_transpose(
    const void* __restrict__ wq, const void* __restrict__ wk,
    const void* __restrict__ wv, const void* __restrict__ wg,
    const void* __restrict__ wo, const int* __restrict__ flagp,
    u16* __restrict__ Wt, u16* __restrict__ wot)
{
  __shared__ u16 T[64 * 72];
  const int flag = *flagp;
  const int t = threadIdx.x;
  const int mat = blockIdx.x >> 4, tile = blockIdx.x & 15;
  const int R0 = (tile >> 2) * 64, C0 = (tile & 3) * 64;
  const void* src = (mat == 0) ? wq : (mat == 1) ? wk : (mat == 2) ? wv
                  : (mat == 3) ? wg : wo;
  u16* dst = (mat < 4) ? (Wt + mat * 65536) : wot;
  {
    int i = t >> 2, j0 = (t & 3) * 16;
    #pragma unroll
    for (int e = 0; e < 8; ++e) {
      float a = ldin(src, (R0 + i) * 256 + C0 + j0 + 2*e,     flag);
      float b = ldin(src, (R0 + i) * 256 + C0 + j0 + 2*e + 1, flag);
      *(unsigned int*)(T + i * 72 + j0 + 2*e) = pk2(a, b);
    }
  }
  __syncthreads();
  {
    int j = t >> 2, i0 = (t & 3) * 16;
    u16 o[16];
    #pragma unroll
    for (int e = 0; e < 16; ++e) o[e] = T[(i0 + e) * 72 + j];
    *(uint4*)(dst + (C0 + j) * 256 + R0 + i0)     = *(const uint4*)o;
    *(uint4*)(dst + (C0 + j) * 256 + R0 + i0 + 8) = *(const uint4*)(o + 8);
  }
}

// ---------------------------------------------------------------------------
// Kernel 1: pair LayerNorm + z[h][q*256+k] via MFMA -> bf16 (1 MB total).
// ---------------------------------------------------------------------------
__global__ __launch_bounds__(256) void k_pair_z(
    const void* __restrict__ pair, const void* __restrict__ png,
    const void* __restrict__ pnb, const void* __restrict__ w2d,
    const int* __restrict__ flagp, u16* __restrict__ z_bf)
{
  __shared__ u16 As[64 * 136];
  __shared__ u16 Bs[16 * 136];
  const int flag = *flagp;
  const int t = threadIdx.x, lane = t & 63, wave = t >> 6;
  const int g = lane >> 4, l15 = lane & 15;
  const int rowBase = blockIdx.x * 64;          // of 65536 (q*256+k)

  if (t < 128) {
    #pragma unroll
    for (int n = 0; n < 16; ++n)
      Bs[n * 136 + t] = (n < 8) ? f2bf(ldin(w2d, t * 8 + n, flag)) : (u16)0;
  }
  {
    int lrow = t >> 2, cb = (t & 3) * 32;
    int base = (rowBase + lrow) * 128 + cb;
    float x[32];
    if (flag) {
      const float* p = (const float*)pair + base;
      #pragma unroll
      for (int j = 0; j < 8; ++j) {
        float4 f4 = *(const float4*)(p + 4 * j);
        x[4*j] = f4.x; x[4*j+1] = f4.y; x[4*j+2] = f4.z; x[4*j+3] = f4.w;
      }
    } else {
      const u16* p = (const u16*)pair + base;
      #pragma unroll
      for (int j = 0; j < 4; ++j) {
        uint4 u = *(const uint4*)(p + 8 * j);
        const u16* h = (const u16*)&u;
        #pragma unroll
        for (int e = 0; e < 8; ++e) x[8*j+e] = bf2f(h[e]);
      }
    }
    float s = 0.f, sq = 0.f;
    #pragma unroll
    for (int j = 0; j < 32; ++j) { s += x[j]; sq += x[j] * x[j]; }
    s  += __shfl_xor(s, 1, 64);  s  += __shfl_xor(s, 2, 64);
    sq += __shfl_xor(sq, 1, 64); sq += __shfl_xor(sq, 2, 64);
    float mu = s * (1.f / 128.f);
    float var = sq * (1.f / 128.f) - mu * mu;
    float rs = rsqrtf(var + 1e-5f);
    float n_[32];
    #pragma unroll
    for (int j = 0; j < 32; ++j) {
      int c = cb + j;
      n_[j] = (x[j] - mu) * rs * ldin(png, c, flag) + ldin(pnb, c, flag);
    }
    u16* dst = As + lrow * 136 + cb;
    #pragma unroll
    for (int j = 0; j < 16; ++j)
      *(unsigned int*)(dst + 2*j) = pk2(n_[2*j], n_[2*j+1]);
  }
  __syncthreads();

  f32x4 accz = {0.f, 0.f, 0.f, 0.f};
  #pragma unroll
  for (int kb = 0; kb < 4; ++kb) {
    bf16x8 a = *(const bf16x8*)(As + (wave * 16 + l15) * 136 + kb * 32 + g * 8);
    bf16x8 b = *(const bf16x8*)(Bs + l15 * 136 + kb * 32 + g * 8);
    accz = __builtin_amdgcn_mfma_f32_16x16x32_bf16(a, b, accz, 0, 0, 0);
  }
  if (l15 < 8) {
    #pragma unroll
    for (int r = 0; r < 4; ++r)
      z_bf[l15 * 65536 + rowBase + wave * 16 + g * 4 + r] = f2bf(accz[r]);
  }
}

// ---------------------------------------------------------------------------
// Kernel 2: msa LayerNorm fully applied -> m_bf16.
// ---------------------------------------------------------------------------
__global__ __launch_bounds__(256) void k_msa_ln(
    const void* __restrict__ msa, const void* __restrict__ qng,
    const void* __restrict__ qnb, const int* __restrict__ flagp,
    u16* __restrict__ m_bf)
{
  const int flag = *flagp;
  int wave = threadIdx.x >> 6, lane = threadIdx.x & 63;
  int row = blockIdx.x * 4 + wave;              // 0..32767
  float x[4];
  if (flag) {
    float4 f4 = *((const float4*)msa + row * 64 + lane);
    x[0]=f4.x; x[1]=f4.y; x[2]=f4.z; x[3]=f4.w;
  } else {
    uint2 u = *((const uint2*)msa + row * 64 + lane);
    const u16* h = (const u16*)&u;
    #pragma unroll
    for (int j = 0; j < 4; ++j) x[j] = bf2f(h[j]);
  }
  float s = 0.f, sq = 0.f;
  #pragma unroll
  for (int j = 0; j < 4; ++j) { s += x[j]; sq += x[j] * x[j]; }
  #pragma unroll
  for (int off = 1; off < 64; off <<= 1) {
    s  += __shfl_xor(s,  off, 64);
    sq += __shfl_xor(sq, off, 64);
  }
  float mu = s * (1.f / 256.f);
  float var = sq * (1.f / 256.f) - mu * mu;
  float rs = rsqrtf(var + 1e-5f);
  float y[4];
  #pragma unroll
  for (int j = 0; j < 4; ++j) {
    int c = lane * 4 + j;
    y[j] = (x[j] - mu) * rs * ldin(qng, c, flag) + ldin(qnb, c, flag);
  }
  uint2 o2;
  o2.x = pk2(y[0], y[1]);
  o2.y = pk2(y[2], y[3]);
  *((uint2*)m_bf + row * 64 + lane) = o2;
}

// ---------------------------------------------------------------------------
// Kernel 3: FUSED projections + attention, one block per (s,h).
// Round-13: R0's af-RESIDENT dense projections (af[8][4] loaded once,
// m_bf read 1x per block, back-to-back MFMA issue — proven 86 µs total)
// + R4's phased in-register attention (swapped-QK pi layout, S[16] dense
// QK, one softmax pass, split-accumulator PV — no Tb scratch, no lgkmcnt
// drains) + R3's sched_barrier(0) qt-guard (provably blocks the zu-hoist
// that spilled R2).  LDS 38.4 KB.
// ---------------------------------------------------------------------------
__global__ __launch_bounds__(256, 2) void k_fused(
    const u16* __restrict__ m_bf, const u16* __restrict__ Wt,
    const void* __restrict__ bg, const u16* __restrict__ z_bf,
    const void* __restrict__ mask, const int* __restrict__ flagp,
    u16* __restrict__ og_ws)
{
  __shared__ u16 Ks[256 * 40];        // [k][d] pad 40        (20480 B)
  __shared__ u16 Vts[32 * 264];       // [d][k] pad 264       (16896 B)
  __shared__ float Mb[256];           // mask bias            ( 1024 B)
  const int flag = *flagp;
  const int t = threadIdx.x, lane = t & 63, wave = t >> 6;
  const int s_ = blockIdx.x, h = blockIdx.y;
  const int g = lane >> 4, l15 = lane & 15;

  Mb[t] = 1e9f * (ldin(mask, s_ * 256 + t, flag) - 1.0f);

  const float scale = 0.17677669529663687f;  // 1/sqrt(32)
  f32x4 zero = {0.f, 0.f, 0.f, 0.f};

  // A fragments: wave's 64 m-rows, full K=256, loaded ONCE (128 VGPRs),
  // reused by all 4 projections (single m_bf HBM read per block).
  bf16x8 af[8][4];
  #pragma unroll
  for (int kb = 0; kb < 8; ++kb)
    #pragma unroll
    for (int mt = 0; mt < 4; ++mt)
      af[kb][mt] = *(const bf16x8*)(
          m_bf + (s_ * 256 + wave * 64 + mt * 16 + l15) * 256 + kb * 32 + g * 8);

  unsigned int qp[4][4];
  float gg[4][2][4];

  // 4 projections sharing af: matid 0=q(swapped) 1=k 2=v(swapped) 3=g
  #pragma unroll
  for (int matid = 0; matid < 4; ++matid) {
    const u16* W = Wt + matid * 65536 + (h * 32) * 256;  // [d][c] rows
    f32x4 acc[4][2];
    #pragma unroll
    for (int mt = 0; mt < 4; ++mt) { acc[mt][0] = zero; acc[mt][1] = zero; }
    #pragma unroll
    for (int kb = 0; kb < 8; ++kb) {
      bf16x8 b0 = *(const bf16x8*)(W + l15 * 256        + kb * 32 + g * 8);
      bf16x8 b1 = *(const bf16x8*)(W + (16 + l15) * 256 + kb * 32 + g * 8);
      #pragma unroll
      for (int mt = 0; mt < 4; ++mt) {
        if (matid == 0 || matid == 2) {
          // swapped: D[d][m-row]: out row g*4+r = d, out col l15 = m-row
          acc[mt][0] = __builtin_amdgcn_mfma_f32_16x16x32_bf16(b0, af[kb][mt], acc[mt][0], 0, 0, 0);
          acc[mt][1] = __builtin_amdgcn_mfma_f32_16x16x32_bf16(b1, af[kb][mt], acc[mt][1], 0, 0, 0);
        } else {
          // normal: out row g*4+r = m-row, out col l15 = d
          acc[mt][0] = __builtin_amdgcn_mfma_f32_16x16x32_bf16(af[kb][mt], b0, acc[mt][0], 0, 0, 0);
          acc[mt][1] = __builtin_amdgcn_mfma_f32_16x16x32_bf16(af[kb][mt], b1, acc[mt][1], 0, 0, 0);
        }
      }
    }
    if (matid == 0) {
      // Q in pi layout: lane holds q = mt*16+l15, d-slots g*4+r / 16+g*4+r
      #pragma unroll
      for (int mt = 0; mt < 4; ++mt) {
        qp[mt][0] = pk2(acc[mt][0][0] * scale, acc[mt][0][1] * scale);
        qp[mt][1] = pk2(acc[mt][0][2] * scale, acc[mt][0][3] * scale);
        qp[mt][2] = pk2(acc[mt][1][0] * scale, acc[mt][1][1] * scale);
        qp[mt][3] = pk2(acc[mt][1][2] * scale, acc[mt][1][3] * scale);
      }
    } else if (matid == 1) {
      #pragma unroll
      for (int mt = 0; mt < 4; ++mt)
        #pragma unroll
        for (int r = 0; r < 4; ++r) {
          int rowl = wave * 64 + mt * 16 + g * 4 + r;   // k row 0..255
          Ks[rowl * 40 + l15]      = f2bf(acc[mt][0][r]);
          Ks[rowl * 40 + 16 + l15] = f2bf(acc[mt][1][r]);
        }
    } else if (matid == 2) {
      // swapped V: lane holds k = wave*64+mt*16+l15, d = g*4+r / 16+g*4+r
      #pragma unroll
      for (int mt = 0; mt < 4; ++mt)
        #pragma unroll
        for (int r = 0; r < 4; ++r) {
          int kcol = wave * 64 + mt * 16 + l15;
          Vts[(g * 4 + r) * 264 + kcol]      = f2bf(acc[mt][0][r]);
          Vts[(16 + g * 4 + r) * 264 + kcol] = f2bf(acc[mt][1][r]);
        }
    } else {
      #pragma unroll
      for (int mt = 0; mt < 4; ++mt)
        #pragma unroll
        for (int nt = 0; nt < 2; ++nt)
          #pragma unroll
          for (int r = 0; r < 4; ++r) {
            float gv = acc[mt][nt][r] + ldin(bg, h * 32 + nt * 16 + l15, flag);
            gg[mt][nt][r] = 1.0f / (1.0f + __expf(-gv));
          }
    }
  }
  __syncthreads();

  // ---- attention: phased, in-register softmax (q = l15 per lane) ----
  #pragma unroll
  for (int qt = 0; qt < 4; ++qt) {
    __builtin_amdgcn_sched_barrier(0);   // no cross-qt hoisting (reg pressure)
    const int qbase = wave * 64 + qt * 16;      // q within s (0..255)
    const u16* zb = z_bf + h * 65536 + (qbase + l15) * 256;
    uint2 zu[16];
    #pragma unroll
    for (int kt = 0; kt < 16; ++kt)
      zu[kt] = *(const uint2*)(zb + kt * 16 + g * 4);

    union { bf16x8 v; unsigned int w[4]; } aq;
    aq.w[0] = qp[qt][0]; aq.w[1] = qp[qt][1];
    aq.w[2] = qp[qt][2]; aq.w[3] = qp[qt][3];

    // Phase 1: dense QK — 16 independent MFMAs (latencies mutually hidden)
    f32x4 S[16];
    #pragma unroll
    for (int kt = 0; kt < 16; ++kt) {
      union { bf16x8 v; uint2 u2[2]; } kf;
      const u16* kr = Ks + (kt * 16 + l15) * 40;
      kf.u2[0] = *(const uint2*)(kr + g * 4);
      kf.u2[1] = *(const uint2*)(kr + 16 + g * 4);
      // St: col l15 = q, row g*4+r = k within kt
      S[kt] = __builtin_amdgcn_mfma_f32_16x16x32_bf16(kf.v, aq.v, zero, 0, 0, 0);
    }

    // Phase 2: softmax (no max-pass: logits bounded; masked -> exp(-1e9)=0)
    float sm = 0.f;
    unsigned int pw[8][4];
    #pragma unroll
    for (int kc = 0; kc < 8; ++kc) {
      #pragma unroll
      for (int half = 0; half < 2; ++half) {
        const int kt = kc * 2 + half;
        float4 mb = *(const float4*)(Mb + kt * 16 + g * 4);
        const u16* zh = (const u16*)&zu[kt];
        float e0 = __expf(S[kt][0] + mb.x + bf2f(zh[0]));
        float e1 = __expf(S[kt][1] + mb.y + bf2f(zh[1]));
        float e2 = __expf(S[kt][2] + mb.z + bf2f(zh[2]));
        float e3 = __expf(S[kt][3] + mb.w + bf2f(zh[3]));
        sm += (e0 + e1) + (e2 + e3);
        pw[kc][half * 2]     = pk2(e0, e1);
        pw[kc][half * 2 + 1] = pk2(e2, e3);
      }
    }

    // Phase 3: dense PV — even/odd kc accumulator split (4 chains)
    f32x4 O0a = zero, O0b = zero, O1a = zero, O1b = zero;
    #pragma unroll
    for (int kc = 0; kc < 8; ++kc) {
      union { bf16x8 v; unsigned int w[4]; } pf;
      pf.w[0] = pw[kc][0]; pf.w[1] = pw[kc][1];
      pf.w[2] = pw[kc][2]; pf.w[3] = pw[kc][3];
      union { bf16x8 v; uint2 u2[2]; } vf0, vf1;
      const u16* vr0 = Vts + l15 * 264 + kc * 32;
      const u16* vr1 = Vts + (16 + l15) * 264 + kc * 32;
      vf0.u2[0] = *(const uint2*)(vr0 + g * 4);
      vf0.u2[1] = *(const uint2*)(vr0 + 16 + g * 4);
      vf1.u2[0] = *(const uint2*)(vr1 + g * 4);
      vf1.u2[1] = *(const uint2*)(vr1 + 16 + g * 4);
      if (kc & 1) {
        O0b = __builtin_amdgcn_mfma_f32_16x16x32_bf16(pf.v, vf0.v, O0b, 0, 0, 0);
        O1b = __builtin_amdgcn_mfma_f32_16x16x32_bf16(pf.v, vf1.v, O1b, 0, 0, 0);
      } else {
        O0a = __builtin_amdgcn_mfma_f32_16x16x32_bf16(pf.v, vf0.v, O0a, 0, 0, 0);
        O1a = __builtin_amdgcn_mfma_f32_16x16x32_bf16(pf.v, vf1.v, O1a, 0, 0, 0);
      }
    }
    sm += __shfl_xor(sm, 16, 64);
    sm += __shfl_xor(sm, 32, 64);
    #pragma unroll
    for (int r = 0; r < 4; ++r) {
      float smr = __shfl(sm, g * 4 + r, 64);
      float inv = 1.0f / smr;
      int qq = qbase + g * 4 + r;
      int base = (s_ * 256 + qq) * 256 + h * 32;
      og_ws[base + l15]      = f2bf((O0a[r] + O0b[r]) * inv * gg[qt][0][r]);
      og_ws[base + 16 + l15] = f2bf((O1a[r] + O1b[r]) * inv * gg[qt][1][r]);
    }
  }
}

// ---------------------------------------------------------------------------
// Kernel 5: output projection GEMM.  64-row tiles, grid (512,2) = 1024
// blocks, ~95 unified regs at launch_bounds(256,4) -> 4 blocks/CU.
// M=32768, N=256, K=256. +bo.
// ---------------------------------------------------------------------------
__global__ __launch_bounds__(256, 4) void k_outproj(
    const u16* __restrict__ og, const u16* __restrict__ wot,
    const void* __restrict__ bo, const int* __restrict__ flagp,
    void* __restrict__ outv)
{
  const int flag = *flagp;
  const int t = threadIdx.x, lane = t & 63, wave = t >> 6;
  const int wm = (wave >> 1) * 32, wn = (wave & 1) * 64;
  const int rowBase = blockIdx.x * 64;
  const int ct = blockIdx.y;
  const int g = lane >> 4, l15 = lane & 15;

  bf16x8 af[8][2];
  #pragma unroll
  for (int kb = 0; kb < 8; ++kb)
    #pragma unroll
    for (int mt = 0; mt < 2; ++mt)
      af[kb][mt] = *(const bf16x8*)(
          og + (rowBase + wm + mt * 16 + l15) * 256 + kb * 32 + g * 8);

  const u16* Wb = wot + (ct * 128 + wn) * 256;
  f32x4 acc[2][4];
  f32x4 zero = {0.f, 0.f, 0.f, 0.f};
  #pragma unroll
  for (int i = 0; i < 2; ++i)
    #pragma unroll
    for (int j = 0; j < 4; ++j) acc[i][j] = zero;
  #pragma unroll
  for (int kb = 0; kb < 8; ++kb) {
    bf16x8 bb[4];
    #pragma unroll
    for (int nt = 0; nt < 4; ++nt)
      bb[nt] = *(const bf16x8*)(Wb + (nt * 16 + l15) * 256 + kb * 32 + g * 8);
    #pragma unroll
    for (int mt = 0; mt < 2; ++mt)
      #pragma unroll
      for (int nt = 0; nt < 4; ++nt)
        acc[mt][nt] = __builtin_amdgcn_mfma_f32_16x16x32_bf16(
            af[kb][mt], bb[nt], acc[mt][nt], 0, 0, 0);
  }
  #pragma unroll
  for (int mt = 0; mt < 2; ++mt)
    #pragma unroll
    for (int nt = 0; nt < 4; ++nt)
      #pragma unroll
      for (int r = 0; r < 4; ++r) {
        int row = rowBase + wm + mt * 16 + g * 4 + r;
        int col = ct * 128 + wn + nt * 16 + l15;
        float val = acc[mt][nt][r] + ldin(bo, col, flag);
        if (flag) ((float*)outv)[row * 256 + col] = val;
        else      ((u16*)outv)[row * 256 + col]   = f2bf(val);
      }
}

// ---------------------------------------------------------------------------
extern "C" void kernel_launch(void* const* d_in, const int* in_sizes, int n_in,
                              void* d_out, int out_size, void* d_ws, size_t ws_size,
                              hipStream_t stream)
{
  const void* msa  = d_in[0];
  const void* pair = d_in[1];
  const void* mask = d_in[2];
  const void* qng  = d_in[3];
  const void* qnb  = d_in[4];
  const void* png  = d_in[5];
  const void* pnb  = d_in[6];
  const void* w2d  = d_in[7];
  const void* wq   = d_in[8];
  const void* wk   = d_in[9];
  const void* wv   = d_in[10];
  const void* wg   = d_in[11];
  const void* bg   = d_in[12];
  const void* wo   = d_in[13];
  const void* bo   = d_in[14];

  char* ws = (char*)d_ws;
  u16* z_bf  = (u16*)(ws + 0);                  //  1,048,576
  u16* Wt    = (u16*)(ws + 1048576);            //    524,288
  u16* wot   = (u16*)(ws + 1572864);            //    131,072
  int* flag  = (int*)(ws + 1703936);            //        256
  u16* m_bf  = (u16*)(ws + 1704192);            // 16,777,216
  u16* og_ws = (u16*)(ws + 18481408);           // 16,777,216 -> ends 35,258,624

  hipLaunchKernelGGL(k_sniff, dim3(1), dim3(64), 0, stream,
                     (const unsigned int*)msa, flag);
  hipLaunchKernelGGL(k_transpose, dim3(80), dim3(256), 0, stream,
                     wq, wk, wv, wg, wo, flag, Wt, wot);
  hipLaunchKernelGGL(k_msa_ln, dim3(8192), dim3(256), 0, stream,
                     msa, qng, qnb, flag, m_bf);
  hipLaunchKernelGGL(k_pair_z, dim3(1024), dim3(256), 0, stream,
                     pair, png, pnb, w2d, flag, z_bf);
  hipLaunchKernelGGL(k_fused, dim3(128, 8), dim3(256), 0, stream,
                     m_bf, Wt, bg, z_bf, mask, flag, og_ws);
  hipLaunchKernelGGL(k_outproj, dim3(512, 2), dim3(256), 0, stream,
                     og_ws, wot, bo, flag, d_out);
}